// Round 1
// baseline (186.940 us; speedup 1.0000x reference)
//
#include <hip/hip_runtime.h>
#include <hip/hip_bf16.h>

#define BB 128
#define NN 36
#define DD 1024
#define HH 16
#define ROWS (BB*NN)          // 4608

typedef __attribute__((ext_vector_type(8))) __bf16 bf16x8;
typedef __attribute__((ext_vector_type(4))) float f32x4;
typedef __attribute__((ext_vector_type(4))) unsigned short us4;

__device__ inline unsigned short f2bf(float f) {
    __hip_bfloat16 h = __float2bfloat16(f);
    return *reinterpret_cast<unsigned short*>(&h);
}

__device__ inline void async16(const unsigned short* g, unsigned short* l) {
    __builtin_amdgcn_global_load_lds((const __attribute__((address_space(1))) unsigned int*)g,
                                     (__attribute__((address_space(3))) unsigned int*)l, 16, 0, 0);
}

// ---------------- prep: roi->bf16, W->bf16, extra  (one launch) ----------------
// grid: [0,4608) roi cvt | [4608,7680) weight cvt | [7680,8328) extra
__global__ __launch_bounds__(256) void prep_kernel(const float* __restrict__ roi,
                                                   const float* __restrict__ Wq,
                                                   const float* __restrict__ Wk,
                                                   const float* __restrict__ Wout,
                                                   const float* __restrict__ pe,
                                                   const float* __restrict__ Wpos,
                                                   const float* __restrict__ bpos,
                                                   const int* __restrict__ adj,
                                                   const float* __restrict__ lbl,
                                                   unsigned short* __restrict__ roi_bf,
                                                   unsigned short* __restrict__ Wcat_bf,
                                                   float* __restrict__ extra) {
    const int bid = blockIdx.x, tid = threadIdx.x;
    if (bid < 4608) {
        int i = bid * 256 + tid;
        f32x4 v = ((const f32x4*)roi)[i];
        us4 o;
        o.x = f2bf(v[0]); o.y = f2bf(v[1]); o.z = f2bf(v[2]); o.w = f2bf(v[3]);
        ((us4*)roi_bf)[i] = o;
        return;
    }
    if (bid < 7680) {
        int wb = bid - 4608;
        int sel = wb >> 10;
        const float* src = sel == 0 ? Wq : (sel == 1 ? Wk : Wout);
        int i = (wb & 1023) * 256 + tid;
        f32x4 v = ((const f32x4*)src)[i];
        us4 o;
        o.x = f2bf(v[0]); o.y = f2bf(v[1]); o.z = f2bf(v[2]); o.w = f2bf(v[3]);
        ((us4*)(Wcat_bf + (size_t)sel * DD * DD))[i] = o;
        return;
    }
    __shared__ __align__(16) float wps[HH * 64];
    __shared__ float bps[HH];
    for (int i = tid; i < HH * 64; i += 256) wps[i] = Wpos[i];
    if (tid < HH) bps[tid] = bpos[tid];
    __syncthreads();

    int idx = (bid - 7680) * 256 + tid;           // one (b,n,m); 165888 total
    f32x4 pr[16];
    const f32x4* pv = (const f32x4*)(pe + (size_t)idx * 64);
#pragma unroll
    for (int j = 0; j < 16; j++) pr[j] = pv[j];
    int a = adj[idx];
    float add = lbl[idx] + (a > 0 ? 0.f : -9e15f);
    int b = idx / 1296, nm = idx % 1296;
    size_t obase = (size_t)b * (16 * 1296) + nm;
    for (int hh = 0; hh < 16; hh++) {
        const f32x4* wv = (const f32x4*)(wps + hh * 64);
        f32x4 acc4 = {0.f, 0.f, 0.f, 0.f};
#pragma unroll
        for (int j = 0; j < 16; j++) acc4 += pr[j] * wv[j];
        float d = acc4[0] + acc4[1] + acc4[2] + acc4[3] + bps[hh];
        d = fmaxf(d, 0.f);
        d = __logf(fmaxf(d, 1e-6f));
        extra[obase + (size_t)hh * 1296] = d + add;
    }
}

// ---------------- fused GEMM + attention ----------------
// One block per (8-batch group, head): M=288 (8x36, exact), N=192 ([q|k|vw] head
// slices), K=1024, BK=64. 512 threads = 8 waves (2M x 4N), wave tile 144x48
// (acc[9][3], same as the 4-wave version). Double-buffered LDS (2x60 KB) with
// depth-1 prefetch + 4-phase schedule per K-tile: {ds_read subtile | issue
// next-tile global_load_lds | barrier | lgkmcnt(0) | setprio(1) MFMA setprio(0) |
// barrier}, vmcnt(0) only once per tile at the boundary (loads get ~3 phases of
// MFMA cover instead of the m97-style immediate drain). Grid 16x16=256 = 1
// block/CU. Phase-split is the T3/T5 regime (guide §5.5): setprio+phase barriers
// only pay in this structure.
__global__ __launch_bounds__(512, 2) void fused_kernel(const unsigned short* __restrict__ A,
                                                       const unsigned short* __restrict__ Wc,
                                                       const float* __restrict__ bq,
                                                       const float* __restrict__ bk,
                                                       const float* __restrict__ extra,
                                                       const float* __restrict__ bout,
                                                       float* __restrict__ out) {
    __shared__ __align__(16) unsigned short pool[61440];   // 122880 B: 2 x (A 18432 + B 12288 shorts)
    const int tid  = threadIdx.x;
    const int wave = tid >> 6, lane = tid & 63;
    const int quad = lane >> 4, l16 = lane & 15;
    const int h  = blockIdx.x & 15;
    const int bg = blockIdx.x >> 4;            // 0..15, 8 batches each
    const int row0 = bg * 288;
    const int wm = wave >> 2, wn = wave & 3;   // 2M x 4N wave grid
    const bool tail = (wave < 4);              // slot j = wave+8*i valid for j<60

    // hoisted staging addresses: slot j = wave + 8*i, i = 0..7
    // A: 2304 chunks (288 rows x 8) = slots 0..35 ; B: 1536 chunks = slots 36..59
    const unsigned short* gsrc[8];
    int loff[8];                               // LDS short-offset within buffer
#pragma unroll
    for (int i = 0; i < 8; i++) {
        int j = wave + 8 * i;
        int jj = j < 60 ? j : 0;               // clamped slots are never issued
        int c = jj * 64 + lane;
        if (jj < 36) {
            int row = c >> 3;
            int col = ((c & 7) ^ (row & 7)) * 8;
            gsrc[i] = A + (size_t)(row0 + row) * DD + col;
            loff[i] = jj * 512;
        } else {
            int cb = c - 2304;
            int row = cb >> 3;
            int sec = row >> 6;
            int wrow = sec * DD + h * 64 + (row & 63);
            int col = ((cb & 7) ^ (row & 7)) * 8;
            gsrc[i] = Wc + (size_t)wrow * DD + col;
            loff[i] = 18432 + (jj - 36) * 512;
        }
    }

    f32x4 acc[9][3] = {};

    // prologue: stage K-tile 0 into buffer 0, full drain once
#pragma unroll
    for (int i = 0; i < 7; i++) async16(gsrc[i], pool + loff[i]);
    if (tail) async16(gsrc[7], pool + loff[7]);
    asm volatile("s_waitcnt vmcnt(0)" ::: "memory");
    __builtin_amdgcn_s_barrier();

#define LDB(ct_, kch_) { int rowb = wn * 48 + (ct_) * 16 + l16; \
    bfv[ct_] = *(const bf16x8*)&cbuf[18432 + rowb * 64 + (((kch_) ^ (rowb & 7)) * 8)]; }
#define LDA(rt_, kch_) { int rowa = wm * 144 + (rt_) * 16 + l16; \
    afv[rt_] = *(const bf16x8*)&cbuf[rowa * 64 + (((kch_) ^ (rowa & 7)) * 8)]; }
#define STAGE(i_) { if ((i_) < 7 || tail) async16(gsrc[i_] + kadv, nbuf + loff[i_]); }
#define PH_WAIT { __builtin_amdgcn_s_barrier(); \
    asm volatile("s_waitcnt lgkmcnt(0)" ::: "memory"); \
    __builtin_amdgcn_sched_barrier(0); }

#pragma unroll 2
    for (int t = 0; t < 16; ++t) {
        unsigned short* cbuf = pool + (t & 1) * 30720;
        unsigned short* nbuf = pool + ((t & 1) ^ 1) * 30720;
        const int kadv = (t + 1) * 64;
        const bool pf = (t < 15);
        bf16x8 bfv[3], afv[9];

        // ---- phase 0: ks0, rt 0..4 (15 MFMA) ----
        LDB(0, quad) LDB(1, quad) LDB(2, quad)
        LDA(0, quad) LDA(1, quad) LDA(2, quad) LDA(3, quad) LDA(4, quad)
        if (pf) { STAGE(0) STAGE(1) STAGE(2) }
        PH_WAIT;
        __builtin_amdgcn_s_setprio(1);
#pragma unroll
        for (int rt = 0; rt < 5; rt++)
#pragma unroll
            for (int ct = 0; ct < 3; ct++)
                acc[rt][ct] = __builtin_amdgcn_mfma_f32_16x16x32_bf16(afv[rt], bfv[ct], acc[rt][ct], 0, 0, 0);
        __builtin_amdgcn_s_setprio(0);
        __builtin_amdgcn_s_barrier();

        // ---- phase 1: ks0, rt 5..8 (12 MFMA) ----
        LDA(5, quad) LDA(6, quad) LDA(7, quad) LDA(8, quad)
        if (pf) { STAGE(3) STAGE(4) STAGE(5) }
        PH_WAIT;
        __builtin_amdgcn_s_setprio(1);
#pragma unroll
        for (int rt = 5; rt < 9; rt++)
#pragma unroll
            for (int ct = 0; ct < 3; ct++)
                acc[rt][ct] = __builtin_amdgcn_mfma_f32_16x16x32_bf16(afv[rt], bfv[ct], acc[rt][ct], 0, 0, 0);
        __builtin_amdgcn_s_setprio(0);
        __builtin_amdgcn_s_barrier();

        // ---- phase 2: ks1, rt 0..4 (15 MFMA) ----
        LDB(0, 4 + quad) LDB(1, 4 + quad) LDB(2, 4 + quad)
        LDA(0, 4 + quad) LDA(1, 4 + quad) LDA(2, 4 + quad) LDA(3, 4 + quad) LDA(4, 4 + quad)
        if (pf) { STAGE(6) STAGE(7) }
        PH_WAIT;
        __builtin_amdgcn_s_setprio(1);
#pragma unroll
        for (int rt = 0; rt < 5; rt++)
#pragma unroll
            for (int ct = 0; ct < 3; ct++)
                acc[rt][ct] = __builtin_amdgcn_mfma_f32_16x16x32_bf16(afv[rt], bfv[ct], acc[rt][ct], 0, 0, 0);
        __builtin_amdgcn_s_setprio(0);
        __builtin_amdgcn_s_barrier();

        // ---- phase 3: ks1, rt 5..8 (12 MFMA) + tile-boundary drain ----
        LDA(5, 4 + quad) LDA(6, 4 + quad) LDA(7, 4 + quad) LDA(8, 4 + quad)
        PH_WAIT;
        __builtin_amdgcn_s_setprio(1);
#pragma unroll
        for (int rt = 5; rt < 9; rt++)
#pragma unroll
            for (int ct = 0; ct < 3; ct++)
                acc[rt][ct] = __builtin_amdgcn_mfma_f32_16x16x32_bf16(afv[rt], bfv[ct], acc[rt][ct], 0, 0, 0);
        __builtin_amdgcn_s_setprio(0);
        asm volatile("s_waitcnt vmcnt(0)" ::: "memory");   // own next-tile stages done
        __builtin_amdgcn_s_barrier();                       // => all waves' stages done
    }
#undef LDB
#undef LDA
#undef STAGE
#undef PH_WAIT

    // ---------------- prefetch extra + bout (hidden under spill + QK) ----------------
    const int bat = wave;                       // 8 waves <-> 8 batches
    const float* exb = extra + ((size_t)((bg * 8 + bat) * 16 + h)) * 1296;
    float exv[3][4][3];
#pragma unroll
    for (int mt = 0; mt < 3; mt++)
#pragma unroll
        for (int r = 0; r < 4; r++) {
            int row = mt * 16 + quad * 4 + r;
#pragma unroll
            for (int nt = 0; nt < 3; nt++) {
                int col = nt * 16 + l16;
                exv[mt][r][nt] = (row < 36 && col < 36) ? exb[row * 36 + col] : 0.f;
            }
        }
    float bo[4];
#pragma unroll
    for (int nt = 0; nt < 4; nt++) bo[nt] = bout[h * 64 + nt * 16 + l16];

    // ---------------- phase 1: spill q,k (stride 72) ----------------
    unsigned short* qL = pool;                 // [288][72]
    unsigned short* kL = pool + 20736;         // [288][72]
#pragma unroll
    for (int ct = 0; ct < 3; ct++) {
        int g = wn * 48 + ct * 16 + l16;
        int sec = g >> 6, e = g & 63;
        if (sec < 2) {
            unsigned short* dst = (sec == 0) ? qL : kL;
            float bias = (sec == 0) ? bq[h * 64 + e] : bk[h * 64 + e];
#pragma unroll
            for (int rt = 0; rt < 9; rt++)
#pragma unroll
                for (int r = 0; r < 4; r++) {
                    int row = wm * 144 + rt * 16 + quad * 4 + r;
                    dst[row * 72 + e] = f2bf(acc[rt][ct][r] + bias);
                }
        }
    }
    __syncthreads();

    // ---------------- phase 2: QK^T per wave (batch = wave) ----------------
    const unsigned short* qB = qL + bat * 36 * 72;
    const unsigned short* kB = kL + bat * 36 * 72;
    int rq[3];
#pragma unroll
    for (int t = 0; t < 3; t++) { int rr = t * 16 + l16; rq[t] = rr < 36 ? rr : 35; }

    f32x4 aff[3][3] = {};
#pragma unroll
    for (int ks = 0; ks < 2; ks++) {
        bf16x8 afr[3], bfr[3];
#pragma unroll
        for (int t = 0; t < 3; t++) afr[t] = *(const bf16x8*)&qB[rq[t] * 72 + ks * 32 + quad * 8];
#pragma unroll
        for (int t = 0; t < 3; t++) bfr[t] = *(const bf16x8*)&kB[rq[t] * 72 + ks * 32 + quad * 8];
#pragma unroll
        for (int mt = 0; mt < 3; mt++)
#pragma unroll
            for (int nt = 0; nt < 3; nt++)
                aff[mt][nt] = __builtin_amdgcn_mfma_f32_16x16x32_bf16(afr[mt], bfr[nt], aff[mt][nt], 0, 0, 0);
    }
    __syncthreads();   // q/k dead; pool becomes vwT | atts

    // ---------------- phase 3: softmax -> atts (stride 56); spill vwT (stride 40) ----------------
    // atts rows 0..47: masked lanes write exact zeros for cols 36..47; rows >=36 are
    // garbage but every consumer discards them.
    unsigned short* vwT   = pool;                        // [8][64][40] = 20480 shorts
    unsigned short* attsL = pool + 20480 + bat * 2688;   // per-batch [48][56]
#pragma unroll
    for (int mt = 0; mt < 3; mt++) {
#pragma unroll
        for (int r = 0; r < 4; r++) {
            int row = mt * 16 + quad * 4 + r;
            float w[3];
#pragma unroll
            for (int nt = 0; nt < 3; nt++) {
                int col = nt * 16 + l16;
                bool valid = (row < 36) && (col < 36);
                w[nt] = valid ? (aff[mt][nt][r] * 0.125f + exv[mt][r][nt]) : -3.4e38f;
            }
            float mx = fmaxf(fmaxf(w[0], w[1]), w[2]);
#pragma unroll
            for (int d = 1; d < 16; d <<= 1) mx = fmaxf(mx, __shfl_xor(mx, d));
            float e0 = __expf(w[0] - mx), e1 = __expf(w[1] - mx), e2 = __expf(w[2] - mx);
            float s = e0 + e1 + e2;
#pragma unroll
            for (int d = 1; d < 16; d <<= 1) s += __shfl_xor(s, d);
            float rs = 1.0f / s;
            attsL[row * 56 + 0  + l16] = f2bf(e0 * rs);
            attsL[row * 56 + 16 + l16] = f2bf(e1 * rs);
            attsL[row * 56 + 32 + l16] = f2bf(e2 * rs);
        }
    }
    // spill vw section into vwT[batch][e][m] (stride 40; m 0..35 real)
#pragma unroll
    for (int ct = 0; ct < 3; ct++) {
        int g = wn * 48 + ct * 16 + l16;
        int sec = g >> 6, e = g & 63;
        if (sec == 2) {
#pragma unroll
            for (int rt = 0; rt < 9; rt++)
#pragma unroll
                for (int r = 0; r < 4; r++) {
                    int row = wm * 144 + rt * 16 + quad * 4 + r;   // 0..287
                    int bb = row / 36, m = row - bb * 36;
                    vwT[bb * 2560 + e * 40 + m] = f2bf(acc[rt][ct][r]);
                }
        }
    }
    __syncthreads();

    // ---------------- phase 4: PV + store ----------------
    const unsigned short* vB = vwT + bat * 2560;
    f32x4 o[3][4] = {};
    {
        bf16x8 pa[3], pb[4], zf = {};
        // ks = 0: m 0..31
#pragma unroll
        for (int mt = 0; mt < 3; mt++) pa[mt] = *(const bf16x8*)&attsL[(mt * 16 + l16) * 56 + quad * 8];
#pragma unroll
        for (int nt = 0; nt < 4; nt++) pb[nt] = *(const bf16x8*)&vB[(nt * 16 + l16) * 40 + quad * 8];
#pragma unroll
        for (int mt = 0; mt < 3; mt++)
#pragma unroll
            for (int nt = 0; nt < 4; nt++)
                o[mt][nt] = __builtin_amdgcn_mfma_f32_16x16x32_bf16(pa[mt], pb[nt], o[mt][nt], 0, 0, 0);
        // ks = 1: m 32..63 (cols 36..47 of atts are exact zeros)
#pragma unroll
        for (int mt = 0; mt < 3; mt++)
            pa[mt] = (quad < 2) ? *(const bf16x8*)&attsL[(mt * 16 + l16) * 56 + 32 + quad * 8] : zf;
#pragma unroll
        for (int nt = 0; nt < 4; nt++)
            pb[nt] = (quad < 2) ? *(const bf16x8*)&vB[(nt * 16 + l16) * 40 + 32 + quad * 8] : zf;
#pragma unroll
        for (int mt = 0; mt < 3; mt++)
#pragma unroll
            for (int nt = 0; nt < 4; nt++)
                o[mt][nt] = __builtin_amdgcn_mfma_f32_16x16x32_bf16(pa[mt], pb[nt], o[mt][nt], 0, 0, 0);
    }

    const size_t obase = (size_t)((bg * 8 + bat) * 36) * DD + h * 64;
#pragma unroll
    for (int mt = 0; mt < 3; mt++)
#pragma unroll
        for (int r = 0; r < 4; r++) {
            int n = mt * 16 + quad * 4 + r;
            if (n < 36) {
#pragma unroll
                for (int nt = 0; nt < 4; nt++)
                    out[obase + (size_t)n * DD + nt * 16 + l16] = o[mt][nt][r] + bo[nt];
            }
        }
}

// ---------------- launcher ----------------
extern "C" void kernel_launch(void* const* d_in, const int* in_sizes, int n_in,
                              void* d_out, int out_size, void* d_ws, size_t ws_size,
                              hipStream_t stream) {
    const float* roi  = (const float*)d_in[0];
    const int*   adj  = (const int*)  d_in[1];
    const float* pe   = (const float*)d_in[2];
    const float* lbl  = (const float*)d_in[3];
    const float* Wq   = (const float*)d_in[4];
    const float* bq   = (const float*)d_in[5];
    const float* Wk   = (const float*)d_in[6];
    const float* bk   = (const float*)d_in[7];
    const float* Wpos = (const float*)d_in[8];
    const float* bpos = (const float*)d_in[9];
    const float* Wout = (const float*)d_in[10];
    const float* bout = (const float*)d_in[11];
    float* out = (float*)d_out;

    char* w = (char*)d_ws;
    unsigned short* roi_bf  = (unsigned short*)(w);               // 9.4 MB
    unsigned short* Wcat_bf = (unsigned short*)(w + 9437184);     // 6.3 MB
    float*          extra   = (float*)(w + 15728640);             // 10.6 MB

    prep_kernel<<<8328, 256, 0, stream>>>(roi, Wq, Wk, Wout, pe, Wpos, bpos, adj, lbl,
                                          roi_bf, Wcat_bf, extra);
    fused_kernel<<<16 * 16, 512, 0, stream>>>(roi_bf, Wcat_bf, bq, bk, extra, bout, out);
}

// Round 2
// 168.624 us; speedup vs baseline: 1.1086x; 1.1086x over previous
//
#include <hip/hip_runtime.h>
#include <hip/hip_bf16.h>

#define BB 128
#define NN 36
#define DD 1024
#define HH 16
#define ROWS (BB*NN)          // 4608

typedef __attribute__((ext_vector_type(8))) __bf16 bf16x8;
typedef __attribute__((ext_vector_type(4))) float f32x4;
typedef __attribute__((ext_vector_type(4))) unsigned short us4;

__device__ inline unsigned short f2bf(float f) {
    __hip_bfloat16 h = __float2bfloat16(f);
    return *reinterpret_cast<unsigned short*>(&h);
}

__device__ inline void async16(const unsigned short* g, unsigned short* l) {
    __builtin_amdgcn_global_load_lds((const __attribute__((address_space(1))) unsigned int*)g,
                                     (__attribute__((address_space(3))) unsigned int*)l, 16, 0, 0);
}

// ---------------- prep: roi->bf16, W->bf16, extra  (one launch) ----------------
// grid: [0,4608) roi cvt | [4608,7680) weight cvt | [7680,8328) extra
__global__ __launch_bounds__(256) void prep_kernel(const float* __restrict__ roi,
                                                   const float* __restrict__ Wq,
                                                   const float* __restrict__ Wk,
                                                   const float* __restrict__ Wout,
                                                   const float* __restrict__ pe,
                                                   const float* __restrict__ Wpos,
                                                   const float* __restrict__ bpos,
                                                   const int* __restrict__ adj,
                                                   const float* __restrict__ lbl,
                                                   unsigned short* __restrict__ roi_bf,
                                                   unsigned short* __restrict__ Wcat_bf,
                                                   float* __restrict__ extra) {
    const int bid = blockIdx.x, tid = threadIdx.x;
    if (bid < 4608) {
        int i = bid * 256 + tid;
        f32x4 v = ((const f32x4*)roi)[i];
        us4 o;
        o.x = f2bf(v[0]); o.y = f2bf(v[1]); o.z = f2bf(v[2]); o.w = f2bf(v[3]);
        ((us4*)roi_bf)[i] = o;
        return;
    }
    if (bid < 7680) {
        int wb = bid - 4608;
        int sel = wb >> 10;
        const float* src = sel == 0 ? Wq : (sel == 1 ? Wk : Wout);
        int i = (wb & 1023) * 256 + tid;
        f32x4 v = ((const f32x4*)src)[i];
        us4 o;
        o.x = f2bf(v[0]); o.y = f2bf(v[1]); o.z = f2bf(v[2]); o.w = f2bf(v[3]);
        ((us4*)(Wcat_bf + (size_t)sel * DD * DD))[i] = o;
        return;
    }
    __shared__ __align__(16) float wps[HH * 64];
    __shared__ float bps[HH];
    for (int i = tid; i < HH * 64; i += 256) wps[i] = Wpos[i];
    if (tid < HH) bps[tid] = bpos[tid];
    __syncthreads();

    int idx = (bid - 7680) * 256 + tid;           // one (b,n,m); 165888 total
    f32x4 pr[16];
    const f32x4* pv = (const f32x4*)(pe + (size_t)idx * 64);
#pragma unroll
    for (int j = 0; j < 16; j++) pr[j] = pv[j];
    int a = adj[idx];
    float add = lbl[idx] + (a > 0 ? 0.f : -9e15f);
    int b = idx / 1296, nm = idx % 1296;
    size_t obase = (size_t)b * (16 * 1296) + nm;
    for (int hh = 0; hh < 16; hh++) {
        const f32x4* wv = (const f32x4*)(wps + hh * 64);
        f32x4 acc4 = {0.f, 0.f, 0.f, 0.f};
#pragma unroll
        for (int j = 0; j < 16; j++) acc4 += pr[j] * wv[j];
        float d = acc4[0] + acc4[1] + acc4[2] + acc4[3] + bps[hh];
        d = fmaxf(d, 0.f);
        d = __logf(fmaxf(d, 1e-6f));
        extra[obase + (size_t)hh * 1296] = d + add;
    }
}

// ---------------- fused GEMM + attention: one block per (4-batch group, head) ----------------
// M=144 (4 batches x 36), N=192 ([q|k|vw] head slices), K=1024, grid 32x16=512,
// 256 threads / 4 waves, 2 blocks/CU (cross-block MFMA∥VMEM overlap, m114).
// GEMM loop: BK=32, double-buffered LDS (2 x 10752 shorts = 43008 B total), T3
// minimum-2-phase: issue next-tile global_load_lds FIRST, then ds_read+MFMA on
// current buffer, then one __syncthreads() (vmcnt drain gets a full tile of
// compute cover instead of round-0's zero cover). Swizzle g(row)=(row>>1)&3 so
// (row parity x chunk) covers the full 128 B bank wrap -> 2-way = free (m136);
// round-1's lockstep 8-wave/1-block restructure regressed (19.6% MfmaUtil) and
// is reverted.
__global__ __launch_bounds__(256, 2) void fused_kernel(const unsigned short* __restrict__ A,
                                                       const unsigned short* __restrict__ Wc,
                                                       const float* __restrict__ bq,
                                                       const float* __restrict__ bk,
                                                       const float* __restrict__ extra,
                                                       const float* __restrict__ bout,
                                                       float* __restrict__ out) {
    __shared__ __align__(16) unsigned short pool[21504];   // 43008 B = 2 x (A 4608 + B 6144 shorts)
    const int tid  = threadIdx.x;
    const int wave = tid >> 6, lane = tid & 63;
    const int quad = lane >> 4, l16 = lane & 15;
    const int h  = blockIdx.x & 15;
    const int bg = blockIdx.x >> 4;            // 0..31, 4 batches each
    const int row0 = bg * 144;

    // hoisted staging addresses: slot j = wave + 4*i, i = 0..5 (j<21 valid)
    // A: 576 chunks (144 rows x 4) = slots 0..8 ; B: 768 chunks (192 x 4) = slots 9..20
    const unsigned short* gsrc[6];
    int loff[6];
#pragma unroll
    for (int i = 0; i < 6; i++) {
        int j = wave + 4 * i;
        int jj = j < 21 ? j : 0;               // clamped slots are never issued
        int c = jj * 64 + lane;
        if (jj < 9) {
            int row = c >> 2, cc = c & 3;
            int col = (cc ^ ((row >> 1) & 3)) * 8;
            gsrc[i] = A + (size_t)(row0 + row) * DD + col;
            loff[i] = jj * 512;
        } else {
            int cb = c - 576;
            int row = cb >> 2, cc = cb & 3;
            int sec = row >> 6;
            int wrow = sec * DD + h * 64 + (row & 63);
            int col = (cc ^ ((row >> 1) & 3)) * 8;
            gsrc[i] = Wc + (size_t)wrow * DD + col;
            loff[i] = 4608 + (jj - 9) * 512;
        }
    }

    f32x4 acc[9][3] = {};

    // prologue: stage K-tile 0 into buffer 0
#pragma unroll
    for (int i = 0; i < 6; i++)
        if (i < 5 || wave == 0) async16(gsrc[i], pool + loff[i]);
    __syncthreads();

#pragma unroll 2
    for (int t = 0; t < 32; ++t) {
        unsigned short* cbuf = pool + (t & 1) * 10752;
        unsigned short* nbuf = pool + ((t & 1) ^ 1) * 10752;
        // phase A: issue next-tile stages early (latency hides under this tile's compute)
        if (t < 31) {
            const int kadv = (t + 1) * 32;
#pragma unroll
            for (int i = 0; i < 6; i++)
                if (i < 5 || wave == 0) async16(gsrc[i] + kadv, nbuf + loff[i]);
        }
        // phase B: ds_read fragments + MFMA on current buffer
        bf16x8 bfv[3], afv[9];
#pragma unroll
        for (int ct = 0; ct < 3; ct++) {
            int rowb = wave * 48 + ct * 16 + l16;
            bfv[ct] = *(const bf16x8*)&cbuf[4608 + rowb * 32 + ((quad ^ ((rowb >> 1) & 3)) * 8)];
        }
#pragma unroll
        for (int rt = 0; rt < 9; rt++) {
            int rowa = rt * 16 + l16;
            afv[rt] = *(const bf16x8*)&cbuf[rowa * 32 + ((quad ^ ((rowa >> 1) & 3)) * 8)];
        }
        __builtin_amdgcn_s_setprio(1);
#pragma unroll
        for (int rt = 0; rt < 9; rt++)
#pragma unroll
            for (int ct = 0; ct < 3; ct++)
                acc[rt][ct] = __builtin_amdgcn_mfma_f32_16x16x32_bf16(afv[rt], bfv[ct], acc[rt][ct], 0, 0, 0);
        __builtin_amdgcn_s_setprio(0);
        __syncthreads();   // drains vmcnt: next-tile stages complete, buffer swap safe
    }

    // ---------------- prefetch extra + bout (hidden under spill + QK) ----------------
    const int bat = wave;
    const float* exb = extra + ((size_t)((bg * 4 + bat) * 16 + h)) * 1296;
    float exv[3][4][3];
#pragma unroll
    for (int mt = 0; mt < 3; mt++)
#pragma unroll
        for (int r = 0; r < 4; r++) {
            int row = mt * 16 + quad * 4 + r;
#pragma unroll
            for (int nt = 0; nt < 3; nt++) {
                int col = nt * 16 + l16;
                exv[mt][r][nt] = (row < 36 && col < 36) ? exb[row * 36 + col] : 0.f;
            }
        }
    float bo[4];
#pragma unroll
    for (int nt = 0; nt < 4; nt++) bo[nt] = bout[h * 64 + nt * 16 + l16];

    // ---------------- phase 1: spill q,k (stride 72) ----------------
    unsigned short* qL = pool;                 // [144][72]
    unsigned short* kL = pool + 10368;         // [144][72]
#pragma unroll
    for (int ct = 0; ct < 3; ct++) {
        int g = wave * 48 + ct * 16 + l16;
        int sec = g >> 6, e = g & 63;
        if (sec < 2) {
            unsigned short* dst = (sec == 0) ? qL : kL;
            float bias = (sec == 0) ? bq[h * 64 + e] : bk[h * 64 + e];
#pragma unroll
            for (int rt = 0; rt < 9; rt++)
#pragma unroll
                for (int r = 0; r < 4; r++) {
                    int row = rt * 16 + quad * 4 + r;
                    dst[row * 72 + e] = f2bf(acc[rt][ct][r] + bias);
                }
        }
    }
    __syncthreads();

    // ---------------- phase 2: QK^T per wave (batch = wave) ----------------
    const unsigned short* qB = qL + bat * 36 * 72;
    const unsigned short* kB = kL + bat * 36 * 72;
    int rq[3];
#pragma unroll
    for (int t = 0; t < 3; t++) { int rr = t * 16 + l16; rq[t] = rr < 36 ? rr : 35; }

    f32x4 aff[3][3] = {};
#pragma unroll
    for (int ks = 0; ks < 2; ks++) {
        bf16x8 afr[3], bfr[3];
#pragma unroll
        for (int t = 0; t < 3; t++) afr[t] = *(const bf16x8*)&qB[rq[t] * 72 + ks * 32 + quad * 8];
#pragma unroll
        for (int t = 0; t < 3; t++) bfr[t] = *(const bf16x8*)&kB[rq[t] * 72 + ks * 32 + quad * 8];
#pragma unroll
        for (int mt = 0; mt < 3; mt++)
#pragma unroll
            for (int nt = 0; nt < 3; nt++)
                aff[mt][nt] = __builtin_amdgcn_mfma_f32_16x16x32_bf16(afr[mt], bfr[nt], aff[mt][nt], 0, 0, 0);
    }
    __syncthreads();   // q/k dead; pool becomes vwT | atts

    // ---------------- phase 3: softmax -> atts (stride 56); spill vwT (stride 40) ----------------
    // atts rows 0..47: masked lanes write exact zeros for cols 36..47; rows >=36 are
    // garbage but every consumer discards them -> no explicit zero-fill needed.
    unsigned short* vwT   = pool;                        // [4][64][40] = 10240 shorts
    unsigned short* attsL = pool + 10240 + bat * 2688;   // per-batch [48][56]
#pragma unroll
    for (int mt = 0; mt < 3; mt++) {
#pragma unroll
        for (int r = 0; r < 4; r++) {
            int row = mt * 16 + quad * 4 + r;
            float w[3];
#pragma unroll
            for (int nt = 0; nt < 3; nt++) {
                int col = nt * 16 + l16;
                bool valid = (row < 36) && (col < 36);
                w[nt] = valid ? (aff[mt][nt][r] * 0.125f + exv[mt][r][nt]) : -3.4e38f;
            }
            float mx = fmaxf(fmaxf(w[0], w[1]), w[2]);
#pragma unroll
            for (int d = 1; d < 16; d <<= 1) mx = fmaxf(mx, __shfl_xor(mx, d));
            float e0 = __expf(w[0] - mx), e1 = __expf(w[1] - mx), e2 = __expf(w[2] - mx);
            float s = e0 + e1 + e2;
#pragma unroll
            for (int d = 1; d < 16; d <<= 1) s += __shfl_xor(s, d);
            float rs = 1.0f / s;
            attsL[row * 56 + 0  + l16] = f2bf(e0 * rs);
            attsL[row * 56 + 16 + l16] = f2bf(e1 * rs);
            attsL[row * 56 + 32 + l16] = f2bf(e2 * rs);
        }
    }
    // spill vw section into vwT[batch][e][m] (stride 40; m 0..35 real)
#pragma unroll
    for (int ct = 0; ct < 3; ct++) {
        int g = wave * 48 + ct * 16 + l16;
        int sec = g >> 6, e = g & 63;
        if (sec == 2) {
#pragma unroll
            for (int rt = 0; rt < 9; rt++)
#pragma unroll
                for (int r = 0; r < 4; r++) {
                    int row = rt * 16 + quad * 4 + r;   // 0..143
                    int bb = row / 36, m = row - bb * 36;
                    vwT[bb * 2560 + e * 40 + m] = f2bf(acc[rt][ct][r]);
                }
        }
    }
    __syncthreads();

    // ---------------- phase 4: PV + store ----------------
    // ks=0 reads atts cols 0..31 (real). ks=1: quads 0,1 read cols 32..47 (36..47 exact
    // zeros); quads 2,3 zero-frag. vwT reads beyond m=39 alias next e-row but multiply
    // by zero atts cols.
    const unsigned short* vB = vwT + bat * 2560;
    f32x4 o[3][4] = {};
    {
        bf16x8 pa[3], pb[4], zf = {};
        // ks = 0: m 0..31
#pragma unroll
        for (int mt = 0; mt < 3; mt++) pa[mt] = *(const bf16x8*)&attsL[(mt * 16 + l16) * 56 + quad * 8];
#pragma unroll
        for (int nt = 0; nt < 4; nt++) pb[nt] = *(const bf16x8*)&vB[(nt * 16 + l16) * 40 + quad * 8];
#pragma unroll
        for (int mt = 0; mt < 3; mt++)
#pragma unroll
            for (int nt = 0; nt < 4; nt++)
                o[mt][nt] = __builtin_amdgcn_mfma_f32_16x16x32_bf16(pa[mt], pb[nt], o[mt][nt], 0, 0, 0);
        // ks = 1: m 32..63
#pragma unroll
        for (int mt = 0; mt < 3; mt++)
            pa[mt] = (quad < 2) ? *(const bf16x8*)&attsL[(mt * 16 + l16) * 56 + 32 + quad * 8] : zf;
#pragma unroll
        for (int nt = 0; nt < 4; nt++)
            pb[nt] = (quad < 2) ? *(const bf16x8*)&vB[(nt * 16 + l16) * 40 + 32 + quad * 8] : zf;
#pragma unroll
        for (int mt = 0; mt < 3; mt++)
#pragma unroll
            for (int nt = 0; nt < 4; nt++)
                o[mt][nt] = __builtin_amdgcn_mfma_f32_16x16x32_bf16(pa[mt], pb[nt], o[mt][nt], 0, 0, 0);
    }

    const size_t obase = (size_t)((bg * 4 + bat) * 36) * DD + h * 64;
#pragma unroll
    for (int mt = 0; mt < 3; mt++)
#pragma unroll
        for (int r = 0; r < 4; r++) {
            int n = mt * 16 + quad * 4 + r;
            if (n < 36) {
#pragma unroll
                for (int nt = 0; nt < 4; nt++)
                    out[obase + (size_t)n * DD + nt * 16 + l16] = o[mt][nt][r] + bo[nt];
            }
        }
}

// ---------------- launcher ----------------
extern "C" void kernel_launch(void* const* d_in, const int* in_sizes, int n_in,
                              void* d_out, int out_size, void* d_ws, size_t ws_size,
                              hipStream_t stream) {
    const float* roi  = (const float*)d_in[0];
    const int*   adj  = (const int*)  d_in[1];
    const float* pe   = (const float*)d_in[2];
    const float* lbl  = (const float*)d_in[3];
    const float* Wq   = (const float*)d_in[4];
    const float* bq   = (const float*)d_in[5];
    const float* Wk   = (const float*)d_in[6];
    const float* bk   = (const float*)d_in[7];
    const float* Wpos = (const float*)d_in[8];
    const float* bpos = (const float*)d_in[9];
    const float* Wout = (const float*)d_in[10];
    const float* bout = (const float*)d_in[11];
    float* out = (float*)d_out;

    char* w = (char*)d_ws;
    unsigned short* roi_bf  = (unsigned short*)(w);               // 9.4 MB
    unsigned short* Wcat_bf = (unsigned short*)(w + 9437184);     // 6.3 MB
    float*          extra   = (float*)(w + 15728640);             // 10.6 MB

    prep_kernel<<<8328, 256, 0, stream>>>(roi, Wq, Wk, Wout, pe, Wpos, bpos, adj, lbl,
                                          roi_bf, Wcat_bf, extra);
    fused_kernel<<<32 * 16, 256, 0, stream>>>(roi_bf, Wcat_bf, bq, bk, extra, bout, out);
}